// Round 6
// baseline (43.039 us; speedup 1.0000x reference)
//
#include <hip/hip_runtime.h>

// ============================================================================
// ROUND 6 = MEASUREMENT ROUND. Identical to R5 except the GEMM K-loop body
// runs rep x2 inside the same dispatch (same outputs, deterministic).
// dur_us - 40.5 isolates the GEMM duration; if >~20us the doubled dispatch
// also surfaces in rocprof top-5 with real counters.
// ============================================================================

#define BB 16
#define TV 256
#define TS 32
#define DD 512

typedef float    floatx4  __attribute__((ext_vector_type(4)));
typedef float    floatx2  __attribute__((ext_vector_type(2)));
typedef short    short8   __attribute__((ext_vector_type(8)));
typedef unsigned short ushort8 __attribute__((ext_vector_type(8)));

#define TANH_SCALE 2.885390082f   // 2*log2(e): tanh(y)=1-2/(exp2(2y*log2e)+1)

static __device__ __forceinline__ unsigned short f2bf(float f) {
    unsigned int u = __float_as_uint(f);
    u += 0x7FFFu + ((u >> 16) & 1u);   // RNE (inputs finite)
    return (unsigned short)(u >> 16);
}

// ---------------------------------------------------------------------------
// Pass 1: convert video/sent/w1/w2 f32 -> bf16 once (memory-bound, ~26 MB).
// ---------------------------------------------------------------------------
__global__ __launch_bounds__(256) void ta_convert(
    const float* __restrict__ video, const float* __restrict__ sent,
    const float* __restrict__ w1,    const float* __restrict__ w2,
    unsigned short* __restrict__ vb, unsigned short* __restrict__ sb,
    unsigned short* __restrict__ w1b, unsigned short* __restrict__ w2b)
{
    const int NV = BB * TV * DD, NS = BB * TS * DD, NW = DD * DD;
    const int base = (blockIdx.x * 256 + threadIdx.x) * 8;
    const float* src; unsigned short* dst; int off;
    if      (base < NV)           { src = video; dst = vb;  off = base; }
    else if (base < NV + NS)      { src = sent;  dst = sb;  off = base - NV; }
    else if (base < NV + NS + NW) { src = w1;    dst = w1b; off = base - NV - NS; }
    else                          { src = w2;    dst = w2b; off = base - NV - NS - NW; }
    const float4 a = *(const float4*)(src + off);
    const float4 b = *(const float4*)(src + off + 4);
    ushort8 o;
    o[0] = f2bf(a.x); o[1] = f2bf(a.y); o[2] = f2bf(a.z); o[3] = f2bf(a.w);
    o[4] = f2bf(b.x); o[5] = f2bf(b.y); o[6] = f2bf(b.z); o[7] = f2bf(b.w);
    *(ushort8*)(dst + off) = o;
}

// ---------------------------------------------------------------------------
// Pass 2: merged bf16-MFMA NT GEMM (R5 structure), body repeated REP=2 times
// within the dispatch for measurement.
// ---------------------------------------------------------------------------
__global__ __launch_bounds__(256) void ta_mfma_gemm(
    const unsigned short* __restrict__ vb, const unsigned short* __restrict__ w1b,
    const float* __restrict__ b1,          const float* __restrict__ vmask,
    float* __restrict__ tmp1,
    const unsigned short* __restrict__ sb, const unsigned short* __restrict__ w2b,
    const float* __restrict__ smask,       unsigned short* __restrict__ tmp2,
    const float* __restrict__ wt,          float* __restrict__ wsum)
{
    const int t = threadIdx.x;

    if (blockIdx.x == 0 && t < 64) {
        float v = 0.f;
        for (int i = t; i < DD; i += 64) v += wt[i];
        for (int off = 32; off; off >>= 1) v += __shfl_down(v, off);
        if (t == 0) wsum[0] = v;
    }

    const bool g2 = (blockIdx.x >= 512);
    const int bid = g2 ? (int)blockIdx.x - 512 : (int)blockIdx.x;
    const unsigned short* __restrict__ A = g2 ? sb    : vb;
    const unsigned short* __restrict__ W = g2 ? w2b   : w1b;
    const float* __restrict__ rm         = g2 ? smask : vmask;
    const int m0 = (g2 ? (bid & 7)  : (bid & 63)) * 64;
    const int n0 = (g2 ? (bid >> 3) : (bid >> 6)) * 64;

    __shared__ unsigned short As[2][4096];   // 2 x 8KB
    __shared__ unsigned short Bs[2][4096];   // 2 x 8KB

    const int lane = t & 63;
    const int wid  = t >> 6;
    const int wm   = wid >> 1, wn = wid & 1;
    const int lr   = lane & 15, kg = lane >> 4;

    const int r0 = t >> 3,          g0c = (t & 7) ^ (r0 & 7);
    const int r1 = (t + 256) >> 3,  g1c = (t & 7) ^ (r1 & 7);
    const unsigned short* a0p = A + (size_t)(m0 + r0) * DD + g0c * 8;
    const unsigned short* a1p = A + (size_t)(m0 + r1) * DD + g1c * 8;
    const unsigned short* w0p = W + (size_t)(n0 + r0) * DD + g0c * 8;
    const unsigned short* w1p = W + (size_t)(n0 + r1) * DD + g1c * 8;
    const int l0 = t * 8;
    const int l1 = (t + 256) * 8;

#define TA_STAGE(buf, koff) do {                                               \
    __builtin_amdgcn_global_load_lds(                                          \
        (const __attribute__((address_space(1))) void*)(a0p + (koff)),         \
        (__attribute__((address_space(3))) void*)&As[buf][l0], 16, 0, 0);      \
    __builtin_amdgcn_global_load_lds(                                          \
        (const __attribute__((address_space(1))) void*)(a1p + (koff)),         \
        (__attribute__((address_space(3))) void*)&As[buf][l1], 16, 0, 0);      \
    __builtin_amdgcn_global_load_lds(                                          \
        (const __attribute__((address_space(1))) void*)(w0p + (koff)),         \
        (__attribute__((address_space(3))) void*)&Bs[buf][l0], 16, 0, 0);      \
    __builtin_amdgcn_global_load_lds(                                          \
        (const __attribute__((address_space(1))) void*)(w1p + (koff)),         \
        (__attribute__((address_space(3))) void*)&Bs[buf][l1], 16, 0, 0);      \
  } while (0)

    floatx4 acc[2][2];

    const int ml0 = wm * 32 + lr, ml1 = ml0 + 16;
    const int nl0 = wn * 32 + lr, nl1 = nl0 + 16;
    const int sa0 = ml0 * 64, sa1 = ml1 * 64;
    const int sb0 = nl0 * 64, sb1 = nl1 * 64;
    const int xa = ml0 & 7, xb = nl0 & 7;

#pragma unroll 1
    for (int rep = 0; rep < 2; ++rep) {   // MEASUREMENT rep-loop (same work)
        acc[0][0] = (floatx4){0.f,0.f,0.f,0.f};
        acc[0][1] = (floatx4){0.f,0.f,0.f,0.f};
        acc[1][0] = (floatx4){0.f,0.f,0.f,0.f};
        acc[1][1] = (floatx4){0.f,0.f,0.f,0.f};

        TA_STAGE(0, 0);
        __syncthreads();

        int cur = 0;
#pragma unroll 1
        for (int step = 0; step < 8; ++step) {
            if (step < 7) TA_STAGE(cur ^ 1, (step + 1) * 64);
#pragma unroll
            for (int kk = 0; kk < 2; ++kk) {
                const int kc = kk * 4 + kg;
                short8 a0 = *(const short8*)&As[cur][sa0 + ((kc ^ xa) << 3)];
                short8 a1 = *(const short8*)&As[cur][sa1 + ((kc ^ xa) << 3)];
                short8 b0 = *(const short8*)&Bs[cur][sb0 + ((kc ^ xb) << 3)];
                short8 b1 = *(const short8*)&Bs[cur][sb1 + ((kc ^ xb) << 3)];
                acc[0][0] = __builtin_amdgcn_mfma_f32_16x16x32_bf16(a0, b0, acc[0][0], 0, 0, 0);
                acc[0][1] = __builtin_amdgcn_mfma_f32_16x16x32_bf16(a0, b1, acc[0][1], 0, 0, 0);
                acc[1][0] = __builtin_amdgcn_mfma_f32_16x16x32_bf16(a1, b0, acc[1][0], 0, 0, 0);
                acc[1][1] = __builtin_amdgcn_mfma_f32_16x16x32_bf16(a1, b1, acc[1][1], 0, 0, 0);
            }
            __syncthreads();
            cur ^= 1;
        }
    }
#undef TA_STAGE

    // epilogue: C row = kg*4 + reg, col = lr; PRESCALED outputs
#pragma unroll
    for (int fm = 0; fm < 2; ++fm)
#pragma unroll
        for (int fn = 0; fn < 2; ++fn)
#pragma unroll
            for (int r = 0; r < 4; ++r) {
                const int m = m0 + wm * 32 + fm * 16 + kg * 4 + r;
                const int n = n0 + wn * 32 + fn * 16 + lr;
                const float mk = rm[m] * TANH_SCALE;
                const float val = acc[fm][fn][r];
                if (!g2) tmp1[(size_t)m * DD + n] = (val + b1[n]) * mk;
                else     tmp2[(size_t)m * DD + n] = f2bf(val * mk);
            }
}

// ---------------------------------------------------------------------------
// Pass 3: fused pairwise tanh reduction (unchanged from R5).
// ---------------------------------------------------------------------------
__global__ __launch_bounds__(512) void ta_tanh_main(
    const float* __restrict__ tmp1,          // [B*TV][D] f32, prescaled
    const unsigned short* __restrict__ tmp2, // [B*TS][D] bf16, prescaled
    const float* __restrict__ wt,            // [D]
    const float* __restrict__ wsum,          // [1]
    const float* __restrict__ vmask,         // [B*TV]
    const float* __restrict__ smask,         // [B*TS]
    float* __restrict__ out)                 // [B][TV][TS]
{
    __shared__ unsigned short t2s[TS * DD];  // 32 KB
    __shared__ float part[512];

    const int t  = threadIdx.x;
    const int b  = blockIdx.x >> 6;
    const int v0 = (blockIdx.x & 63) << 2;

    {
        const unsigned short* src = tmp2 + (size_t)b * TS * DD;
#pragma unroll
        for (int i = 0; i < 4; ++i) {
            const int chunk = t + 512 * i;
            const int row = chunk >> 6;
            const int c   = chunk & 63;
            ushort8 val = *(const ushort8*)&src[chunk * 8];
            *(ushort8*)&t2s[row * DD + ((c ^ (row & 15)) << 3)] = val;
        }
    }
    __syncthreads();

    const int s  = t & 31;
    const int vi = (t >> 5) & 3;
    const int q  = __builtin_amdgcn_readfirstlane(t >> 7);
    const int v  = v0 + vi;

    const float pm = vmask[b * TV + v] * smask[b * TS + s];
    const float* __restrict__ x1p = tmp1 + ((size_t)(b * TV + v)) * DD + q * 128;
    const float* __restrict__ wtp = wt + q * 128;
    const int rowbase = s * DD;
    const int swz = s & 15;

    floatx4 acc4a = {0.f, 0.f, 0.f, 0.f};
    floatx4 acc4b = {0.f, 0.f, 0.f, 0.f};
#pragma unroll 2
    for (int i = 0; i < 16; ++i) {
        uint4 u4 = *(const uint4*)&t2s[rowbase + (((q * 16 + i) ^ swz) << 3)];
        floatx4 x1a = *(const floatx4*)(x1p + i * 8);
        floatx4 x1b = *(const floatx4*)(x1p + i * 8 + 4);
        floatx4 wa  = *(const floatx4*)(wtp + i * 8);
        floatx4 wb  = *(const floatx4*)(wtp + i * 8 + 4);
        floatx4 x2a = { __uint_as_float(u4.x << 16), __uint_as_float(u4.x & 0xffff0000u),
                        __uint_as_float(u4.y << 16), __uint_as_float(u4.y & 0xffff0000u) };
        floatx4 x2b = { __uint_as_float(u4.z << 16), __uint_as_float(u4.z & 0xffff0000u),
                        __uint_as_float(u4.w << 16), __uint_as_float(u4.w & 0xffff0000u) };
        floatx4 za = x1a + x2a;
        floatx4 zb = x1b + x2b;
        floatx4 ea = { __builtin_amdgcn_exp2f(za[0]), __builtin_amdgcn_exp2f(za[1]),
                       __builtin_amdgcn_exp2f(za[2]), __builtin_amdgcn_exp2f(za[3]) };
        floatx4 eb = { __builtin_amdgcn_exp2f(zb[0]), __builtin_amdgcn_exp2f(zb[1]),
                       __builtin_amdgcn_exp2f(zb[2]), __builtin_amdgcn_exp2f(zb[3]) };
        ea = ea + 1.f;
        eb = eb + 1.f;
        floatx4 ra = { __builtin_amdgcn_rcpf(ea[0]), __builtin_amdgcn_rcpf(ea[1]),
                       __builtin_amdgcn_rcpf(ea[2]), __builtin_amdgcn_rcpf(ea[3]) };
        floatx4 rb = { __builtin_amdgcn_rcpf(eb[0]), __builtin_amdgcn_rcpf(eb[1]),
                       __builtin_amdgcn_rcpf(eb[2]), __builtin_amdgcn_rcpf(eb[3]) };
        acc4a = acc4a + wa * ra;
        acc4b = acc4b + wb * rb;
    }

    part[t] = (acc4a[0] + acc4a[1]) + (acc4a[2] + acc4a[3])
            + (acc4b[0] + acc4b[1]) + (acc4b[2] + acc4b[3]);
    __syncthreads();

    if (t < 128) {
        const float sum = part[t] + part[t + 128] + part[t + 256] + part[t + 384];
        const int s2 = t & 31, vi2 = t >> 5;
        const int v2 = v0 + vi2;
        const float pm2 = vmask[b * TV + v2] * smask[b * TS + s2];
        out[((size_t)b * TV + v2) * TS + s2] = pm2 * (wsum[0] - 2.f * sum);
    }
}

// ---------------------------------------------------------------------------
extern "C" void kernel_launch(void* const* d_in, const int* in_sizes, int n_in,
                              void* d_out, int out_size, void* d_ws, size_t ws_size,
                              hipStream_t stream)
{
    const float* video = (const float*)d_in[0];
    const float* vmask = (const float*)d_in[1];
    const float* sent  = (const float*)d_in[2];
    const float* smask = (const float*)d_in[3];
    const float* w1    = (const float*)d_in[4];
    const float* b1    = (const float*)d_in[5];
    const float* w2    = (const float*)d_in[6];
    const float* wt    = (const float*)d_in[7];
    float* out = (float*)d_out;

    const size_t NV = (size_t)BB * TV * DD, NS = (size_t)BB * TS * DD, NW = (size_t)DD * DD;

    float* tmp1          = (float*)d_ws;            // 8 MB f32 (prescaled)
    unsigned short* tmp2 = (unsigned short*)(tmp1 + NV);  // 512 KB bf16 (prescaled)
    unsigned short* vb   = tmp2 + NS;               // 4 MB
    unsigned short* sb   = vb + NV;                 // 512 KB
    unsigned short* w1b  = sb + NS;                 // 512 KB
    unsigned short* w2b  = w1b + NW;                // 512 KB
    float* wsum          = (float*)(w2b + NW);      // 4 B

    const int total8 = (int)((NV + NS + 2 * NW) / 8);   // 360448
    ta_convert<<<dim3(total8 / 256), dim3(256), 0, stream>>>(
        video, sent, w1, w2, vb, sb, w1b, w2b);
    ta_mfma_gemm<<<dim3(512 + 64), dim3(256), 0, stream>>>(
        vb, w1b, b1, vmask, tmp1, sb, w2b, smask, tmp2, wt, wsum);
    ta_tanh_main<<<dim3(BB * (TV / 4)), dim3(512), 0, stream>>>(
        tmp1, tmp2, wt, wsum, vmask, smask, out);
}